// Round 2
// baseline (117.451 us; speedup 1.0000x reference)
//
#include <hip/hip_runtime.h>

// DiffVolumeV2: out[b][c][d][h][x] = left[b][c][h][x] - right[b][c][h][clip(4x-d+1, 0, Wr-1)]
// B=4, C=32, H=80, Wl=160, Wr=640, D=48 (D derived from out_size at launch).
// Store-BW-bound: 314.6 MB out + 32.8 MB in => ~53us floor @ 6.5 TB/s.
//
// Layout insight: out is [B,C,D,H,Wl] -> for fixed (b,c,d) the (h,x) plane is
// contiguous. Block = (b,c, 8 consecutive h rows), thread = (h_local, x-group).
// Then each d-iteration stores 320 contiguous float4 (20KB), every wave store
// a perfectly coalesced 1KiB run. Left fragment + gather base index hoisted
// out of the d-loop; inner loop is 4 LDS reads + 1 float4 store.

constexpr int Bc  = 4;
constexpr int Cc  = 32;
constexpr int Hc  = 80;
constexpr int WLc = 160;
constexpr int WRc = 640;
constexpr int HB  = 8;                 // h rows per block
constexpr int TPB = HB * (WLc / 4);    // 320 threads = 5 waves, 1 thread per (h_local, group)
constexpr int RPAD = WRc + WRc / 32;   // 660: pad addr = i + (i>>5) kills stride-16 bank conflicts

template<int DFIX>
__global__ __launch_bounds__(TPB) void diffvol_kernel(
    const float* __restrict__ left, const float* __restrict__ right,
    float* __restrict__ out, int Ddyn)
{
    const int D = DFIX ? DFIX : Ddyn;

    __shared__ __align__(16) float lrow[HB * WLc];   // 1280 floats, linear (float4-read)
    __shared__ float rrow[HB * RPAD];                // 8 padded right rows (20.6 KB)

    constexpr int NHB = Hc / HB;       // 10 h-chunks
    const int blk = blockIdx.x;        // bc * NHB + hb
    const int hb  = blk % NHB;
    const int bc  = blk / NHB;
    const int h0  = hb * HB;

    const float* lp = left  + ((size_t)bc * Hc + h0) * WLc;
    const float* rp = right + ((size_t)bc * Hc + h0) * WRc;

    const int tid = threadIdx.x;

    // Stage left: 1280 floats = exactly 1 float4 per thread, linear LDS.
    {
        float4 v = *(const float4*)(lp + tid * 4);
        *(float4*)(lrow + tid * 4) = v;
    }
    // Stage right: 5120 floats = 4 float4 loads per thread, scalar padded LDS writes.
    #pragma unroll
    for (int it = 0; it < (HB * WRc / 4) / TPB; ++it) {
        int i   = tid + it * TPB;              // float4 index
        int row = i / (WRc / 4);
        int c4  = (i - row * (WRc / 4)) * 4;
        float4 v = *(const float4*)(rp + row * WRc + c4);
        float* dst = rrow + row * RPAD;
        const float* vv = (const float*)&v;
        #pragma unroll
        for (int k = 0; k < 4; ++k) {
            int c = c4 + k;
            dst[c + (c >> 5)] = vv[k];
        }
    }
    __syncthreads();

    // Per-thread fixed coordinates: tid = h_local * 40 + g
    const int hl = tid / (WLc / 4);
    const int g  = tid - hl * (WLc / 4);
    const float4 lv = *(const float4*)(lrow + tid * 4);   // hoisted: d-independent
    const float* rb = rrow + hl * RPAD;
    const int r0 = 16 * g + 1;                            // gather col for j=0 at d=0

    // out base: ((bc*D + d)*H + h0 + hl)*Wl + g*4 = bc*D*H*Wl + h0*Wl + tid*4 + d*H*Wl
    float* ob = out + (size_t)bc * D * (Hc * WLc) + h0 * WLc + tid * 4;
    const float* lvp = (const float*)&lv;

    #pragma unroll 4
    for (int d = 0; d < D; ++d) {
        float4 v;
        float* vp = (float*)&v;
        #pragma unroll
        for (int j = 0; j < 4; ++j) {
            int c = r0 + 4 * j - d;            // max 637 < 639: upper clip unreachable
            c = c < 0 ? 0 : c;
            vp[j] = lvp[j] - rb[c + (c >> 5)];
        }
        *(float4*)(ob + (size_t)d * (Hc * WLc)) = v;
    }
}

extern "C" void kernel_launch(void* const* d_in, const int* in_sizes, int n_in,
                              void* d_out, int out_size, void* d_ws, size_t ws_size,
                              hipStream_t stream) {
    const float* left  = (const float*)d_in[0];
    const float* right = (const float*)d_in[1];
    float* out = (float*)d_out;

    const int D = out_size / (Bc * Cc * Hc * WLc);   // 48 for the reference shapes

    dim3 grid(Bc * Cc * (Hc / HB));   // 1280 blocks = exactly 5 per CU, homogeneous
    if (D == 48) {
        diffvol_kernel<48><<<grid, TPB, 0, stream>>>(left, right, out, D);
    } else {
        diffvol_kernel<0><<<grid, TPB, 0, stream>>>(left, right, out, D);
    }
}

// Round 3
// 69.504 us; speedup vs baseline: 1.6898x; 1.6898x over previous
//
#include <hip/hip_runtime.h>

// DiffVolumeV2: out[b][c][d][h][x] = left[b][c][h][x] - right[b][c][h][clip(4x-d+1, 0, Wr-1)]
// B=4, C=32, H=80, Wl=160, Wr=640, D=48.
// Store-BW-bound: 314.6 MB out + 32.8 MB in => ~54us floor @ 6.5 TB/s.
//
// Round-2 lesson: 1280 big blocks with per-thread d-walk regressed to 117us.
// Round-1 layout (block=(b,c,h) row, 10240 blocks, t->(d,g)) measured 72.5us;
// this round keeps that layout and removes its per-iteration overhead:
//  - no magic-div in the loop: t+=256 <=> g+=16 (mod 40) -> incremental (g, e=16g-d, ptr)
//  - full static unroll: 7 slots + 1 wave-uniform guarded slot (tid<128 = waves 0,1)
//  - float4 right-row staging

constexpr int Bc  = 4;
constexpr int Cc  = 32;
constexpr int Hc  = 80;
constexpr int WLc = 160;
constexpr int WRc = 640;
constexpr int TPB = 256;
constexpr int GROUPS = WLc / 4;          // 40 float4 groups per row
constexpr int RPAD = WRc + WRc / 32;     // 660: addr = i + (i>>5) kills stride-16 conflicts

__global__ __launch_bounds__(TPB) void diffvol48(
    const float* __restrict__ left, const float* __restrict__ right,
    float* __restrict__ out)
{
    constexpr int D = 48;
    __shared__ __align__(16) float lrow[WLc];
    __shared__ float rrow[RPAD];

    const int blk = blockIdx.x;          // bc*80 + h
    const int h   = blk % Hc;
    const int bc  = blk / Hc;
    const float* lp = left  + ((size_t)bc * Hc + h) * WLc;
    const float* rp = right + ((size_t)bc * Hc + h) * WRc;
    const int tid = threadIdx.x;

    if (tid < GROUPS)
        *(float4*)(lrow + tid * 4) = *(const float4*)(lp + tid * 4);
    if (tid < WRc / 4) {
        float4 v = *(const float4*)(rp + tid * 4);
        const float* vv = (const float*)&v;
        #pragma unroll
        for (int k = 0; k < 4; ++k) { int c = tid * 4 + k; rrow[c + (c >> 5)] = vv[k]; }
    }
    __syncthreads();

    int d = tid / GROUPS;                // 0..6 (one div, outside loop)
    int g = tid - d * GROUPS;            // 0..39
    int e = 16 * g - d;                  // gather base; c_j = e + 1 + 4j
    // out element offset: ((bc*D + d)*Hc + h)*WLc + g*4
    float* op = out + (size_t)bc * (D * Hc * WLc) + h * WLc
                    + (size_t)d * (Hc * WLc) + g * 4;

    // t += 256  <=>  g += 16 mod 40; no-wrap: d+=6, wrap: d+=7.
    //   de   = e' - e  : no-wrap 16*16-6 = 250   | wrap 16*(-24)-7 = -391
    //   dofs = op' - op: no-wrap 6*12800+64      | wrap 7*12800-96
    #define SLOT_BODY                                                     \
    {                                                                     \
        const float4 lv = *(const float4*)(lrow + g * 4);                 \
        const float* lvp = (const float*)&lv;                             \
        float4 v; float* vp = (float*)&v;                                 \
        _Pragma("unroll")                                                 \
        for (int j = 0; j < 4; ++j) {                                     \
            int c = e + 1 + 4 * j;                                        \
            c = c < 0 ? 0 : c;                                            \
            vp[j] = lvp[j] - rrow[c + (c >> 5)];                          \
        }                                                                 \
        *(float4*)op = v;                                                 \
    }
    #define SLOT_ADVANCE                                                  \
    {                                                                     \
        int gn = g + 16;                                                  \
        bool wrap = gn >= GROUPS;                                         \
        g = wrap ? gn - GROUPS : gn;                                      \
        e += wrap ? -391 : 250;                                           \
        op += wrap ? (7 * Hc * WLc - 96) : (6 * Hc * WLc + 64);           \
    }

    #pragma unroll
    for (int it = 0; it < 7; ++it) { SLOT_BODY; SLOT_ADVANCE; }
    if (tid < (D * GROUPS - 7 * TPB)) {  // tid < 128: waves 0,1 — uniform per wave
        SLOT_BODY;
    }
    #undef SLOT_BODY
    #undef SLOT_ADVANCE
}

// Generic fallback (any D): round-1 proven kernel.
__global__ __launch_bounds__(TPB) void diffvol_generic(
    const float* __restrict__ left, const float* __restrict__ right,
    float* __restrict__ out, int D)
{
    __shared__ __align__(16) float lrow[WLc];
    __shared__ float rrow[RPAD];

    const int blk = blockIdx.x;
    const int h   = blk % Hc;
    const int bc  = blk / Hc;
    const float* lp = left  + ((size_t)bc * Hc + h) * WLc;
    const float* rp = right + ((size_t)bc * Hc + h) * WRc;
    const int tid = threadIdx.x;

    if (tid < WLc) lrow[tid] = lp[tid];
    for (int i = tid; i < WRc; i += TPB) rrow[i + (i >> 5)] = rp[i];
    __syncthreads();

    float* ob = out + ((size_t)bc * D * Hc + h) * WLc;
    const int total = D * GROUPS;
    for (int t = tid; t < total; t += TPB) {
        const int d  = t / GROUPS;
        const int g  = t - d * GROUPS;
        const int x0 = g * 4;
        const float4 lv = *(const float4*)(lrow + x0);
        float4 v;
        float* vp = (float*)&v;
        const float* lvp = (const float*)&lv;
        #pragma unroll
        for (int j = 0; j < 4; ++j) {
            int r = 4 * (x0 + j) - d + 1;
            r = r < 0 ? 0 : r;
            vp[j] = lvp[j] - rrow[r + (r >> 5)];
        }
        *(float4*)(ob + (size_t)d * (Hc * WLc) + x0) = v;
    }
}

extern "C" void kernel_launch(void* const* d_in, const int* in_sizes, int n_in,
                              void* d_out, int out_size, void* d_ws, size_t ws_size,
                              hipStream_t stream) {
    const float* left  = (const float*)d_in[0];
    const float* right = (const float*)d_in[1];
    float* out = (float*)d_out;

    const int D = out_size / (Bc * Cc * Hc * WLc);

    dim3 grid(Bc * Cc * Hc);   // 10240 blocks, one per (b,c,h) row
    if (D == 48) {
        diffvol48<<<grid, TPB, 0, stream>>>(left, right, out);
    } else {
        diffvol_generic<<<grid, TPB, 0, stream>>>(left, right, out, D);
    }
}